// Round 13
// baseline (636.779 us; speedup 1.0000x reference)
//
#include <hip/hip_runtime.h>

// Sinkhorn EMD, B=8, N=2048, eps=0.005, 50 iters.
// R13 = R12 + two latency-chain fixes:
//  (1) distributed-arrival barrier: block stores pass# to its OWN slot
//      (parallel, no same-address RMW serialization); wave0 polls all 32
//      slots at once via lanes + ballot.
//  (2) sparse fast path: all-4-rows cnt<=128 -> fully unrolled 8-gather
//      straight-line block (loads issue together, 1 exposed IC round trip).
// Everything else identical to R12 (604us, absmax 0.0): gather-only,
// IC-coherent atomics, register-resident row state, online 0-5,
// builds {6,7}+24k, MARGIN=48, CAP=256.

#define BB 8
#define NN 2048
#define NPASS 100
#define ONLINE_PASSES 6
#define RPW 4
#define GRID_BLOCKS 256
#define BLOCKS_PER_BATCH 32
#define TPB 1024
#define CAP 256
#define MARGIN 48.0f

constexpr float EPSV = 0.005f;
constexpr float KS   = EPSV * 0.69314718055994531f; // eps*ln2
constexpr float INVK = 1.0f / KS;
constexpr float C1V  = -EPSV * 7.6246189861593985f; // eps*log(1/2048)
constexpr float C1K  = C1V * INVK;
constexpr float KQ4  = KS * 0.25f;
constexpr float TWOI = 2.0f * INVK;
constexpr float HK   = KS * 0.5f;

__device__ __forceinline__ float fexp2(float x) { return __builtin_amdgcn_exp2f(x); }
__device__ __forceinline__ float flog2(float x) { return __builtin_amdgcn_logf(x); }

__device__ __forceinline__ float cohLoad(const float* p) {
    return __hip_atomic_load(p, __ATOMIC_RELAXED, __HIP_MEMORY_SCOPE_AGENT);
}
__device__ __forceinline__ void cohStore(float* p, float v) {
    __hip_atomic_store(p, v, __ATOMIC_RELAXED, __HIP_MEMORY_SCOPE_AGENT);
}
__device__ __forceinline__ int cohLoadI(const int* p) {
    return __hip_atomic_load(p, __ATOMIC_RELAXED, __HIP_MEMORY_SCOPE_AGENT);
}
__device__ __forceinline__ void cohStoreI(int* p, int v) {
    __hip_atomic_store(p, v, __ATOMIC_RELAXED, __HIP_MEMORY_SCOPE_AGENT);
}

// Distributed-arrival barrier: block rb stores `target` to its own slot;
// wave0's lanes poll all 32 slots in parallel. vmcnt drained by the
// preceding __syncthreads (same visibility argument validated R6-R12).
__device__ __forceinline__ void barrier_sync(int* arr, int rb, int target) {
    __syncthreads();
    if (threadIdx.x < 64) {
        if (threadIdx.x == 0) cohStoreI(&arr[rb], target);
        const int slot = threadIdx.x & 31;
        while (true) {
            int v = cohLoadI(&arr[slot]);
            if (__ballot(v >= target) == ~0ull) break;
            __builtin_amdgcn_s_sleep(1);
        }
    }
    __syncthreads();
}

// classic monotonic-counter barrier (single final use, 256 blocks)
__device__ __forceinline__ void barrier_ctr(int* ctr, int target) {
    __syncthreads();
    if (threadIdx.x == 0) {
        __hip_atomic_fetch_add(ctr, 1, __ATOMIC_RELAXED, __HIP_MEMORY_SCOPE_AGENT);
        while (__hip_atomic_load(ctr, __ATOMIC_RELAXED, __HIP_MEMORY_SCOPE_AGENT) < target) {
            __builtin_amdgcn_s_sleep(1);
        }
    }
    __syncthreads();
}

__global__ void __launch_bounds__(TPB, 4) emd_persist(
    const float* __restrict__ preds, const float* __restrict__ gts,
    float* __restrict__ fpot, float* __restrict__ gpot,
    float* __restrict__ partials, int* __restrict__ barArr, int* __restrict__ gctr,
    float* __restrict__ out)
{
    __shared__ float4 sjall[2 * NN];
    __shared__ float  sa[NN];
    __shared__ float  wred[16];
    __shared__ unsigned short slist[2][64][CAP];

    const int blk  = blockIdx.x;
    const int b    = blk & 7;
    const int rb   = blk >> 3;
    const int wave = threadIdx.x >> 6;
    const int lane = threadIdx.x & 63;
    const int rowL0 = wave * RPW;
    const int row0  = rb * 64 + rowL0;

    const float* pb  = preds + (size_t)b * NN * 3;
    const float* gbp = gts   + (size_t)b * NN * 3;
    float* fb = fpot + (size_t)b * NN;
    float* gb = gpot + (size_t)b * NN;
    int*   bar = barArr + b * 64;            // 32 slots used, 256B stride

    for (int t = threadIdx.x; t < NN; t += TPB) {
        float gx = gbp[3*t], gy = gbp[3*t+1], gz = gbp[3*t+2];
        float Gx = gx*TWOI, Gy = gy*TWOI, Gz = gz*TWOI;
        sjall[t] = make_float4(Gx, Gy, Gz, -KQ4*(Gx*Gx+Gy*Gy+Gz*Gz));
        float qx = pb[3*t], qy = pb[3*t+1], qz = pb[3*t+2];
        float Qx = qx*TWOI, Qy = qy*TWOI, Qz = qz*TWOI;
        sjall[NN+t] = make_float4(Qx, Qy, Qz, -KQ4*(Qx*Qx+Qy*Qy+Qz*Qz));
    }
    __syncthreads();

    float qxf[RPW], qyf[RPW], qzf[RPW], pcf[RPW];
    float qxg[RPW], qyg[RPW], qzg[RPW], pcg[RPW];
#pragma unroll
    for (int r = 0; r < RPW; ++r) {
        float4 df = sjall[NN + row0 + r];
        qxf[r] = HK*df.x; qyf[r] = HK*df.y; qzf[r] = HK*df.z;
        pcf[r] = C1V - KS*df.w;
        float4 dg = sjall[row0 + r];
        qxg[r] = HK*dg.x; qyg[r] = HK*dg.y; qzg[r] = HK*dg.z;
        pcg[r] = C1V - KS*dg.w;
    }
    float LpF[RPW] = {0,0,0,0}, LpG[RPW] = {0,0,0,0};
    int   cnF[RPW] = {0,0,0,0}, cnG[RPW] = {0,0,0,0};

#pragma unroll 1
    for (int pass = 0; pass < NPASS; ++pass) {
        const int odd = pass & 1;
        const int colOff = odd ? NN : 0;
        const float* pin  = odd ? fb : gb;
        float*       pout = odd ? gb : fb;
        const bool isBuild  = (pass >= ONLINE_PASSES) &&
                              (((pass - ONLINE_PASSES) % 24) < 2);
        const bool isSparse = (pass >= ONLINE_PASSES) && !isBuild;

        float qx[RPW], qy[RPW], qz[RPW], pc[RPW], M[RPW];
#pragma unroll
        for (int r = 0; r < RPW; ++r) {
            qx[r] = odd ? qxg[r] : qxf[r];
            qy[r] = odd ? qyg[r] : qyf[r];
            qz[r] = odd ? qzg[r] : qzf[r];
            pc[r] = odd ? pcg[r] : pcf[r];
            M[r]  = odd ? LpG[r] : LpF[r];
        }

        if (isSparse) {
            const int c0 = odd ? cnG[0] : cnF[0];
            const int c1 = odd ? cnG[1] : cnF[1];
            const int c2 = odd ? cnG[2] : cnF[2];
            const int c3 = odd ? cnG[3] : cnF[3];
            float s4[RPW], L[RPW];

            if (c0 <= 128 && c1 <= 128 && c2 <= 128 && c3 <= 128) {
                // ---- straight-line: 8 gathers issue together ----
                const int cnt[RPW] = {c0, c1, c2, c3};
                int jA[RPW], jB[RPW];
#pragma unroll
                for (int r = 0; r < RPW; ++r) {
                    const unsigned short* lb = slist[odd][rowL0 + r];
                    int kA = lane, kB = lane + 64;
                    jA[r] = lb[kA < cnt[r] ? kA : 0];
                    jB[r] = lb[kB < cnt[r] ? kB : 0];
                }
                float4 dA[RPW], dB[RPW];
                float  pA[RPW], pB[RPW];
#pragma unroll
                for (int r = 0; r < RPW; ++r) {
                    dA[r] = sjall[colOff + jA[r]];
                    dB[r] = sjall[colOff + jB[r]];
                    pA[r] = cohLoad(&pin[jA[r]]);
                    pB[r] = cohLoad(&pin[jB[r]]);
                }
#pragma unroll
                for (int r = 0; r < RPW; ++r) {
                    float xA = fmaf(qx[r], dA[r].x, fmaf(qy[r], dA[r].y,
                               fmaf(qz[r], dA[r].z, fmaf(pA[r], INVK, dA[r].w))));
                    float xB = fmaf(qx[r], dB[r].x, fmaf(qy[r], dB[r].y,
                               fmaf(qz[r], dB[r].z, fmaf(pB[r], INVK, dB[r].w))));
                    float eA = (lane      < cnt[r]) ? fexp2(fminf(xA - M[r], 100.f)) : 0.f;
                    float eB = (lane + 64 < cnt[r]) ? fexp2(fminf(xB - M[r], 100.f)) : 0.f;
                    s4[r] = eA + eB;
                }
            } else {
                // ---- general per-row loops (rare) ----
#pragma unroll
                for (int r = 0; r < RPW; ++r) {
                    const int cnt = odd ? cnG[r] : cnF[r];
                    const unsigned short* lb = slist[odd][rowL0 + r];
                    float s1 = 0.f;
                    if (cnt <= CAP) {
#pragma unroll 1
                        for (int k = lane; k < cnt; k += 64) {
                            int j = lb[k];
                            float4 d = sjall[colOff + j];
                            float aw = fmaf(cohLoad(&pin[j]), INVK, d.w);
                            float x  = fmaf(qx[r], d.x, fmaf(qy[r], d.y, fmaf(qz[r], d.z, aw)));
                            s1 += fexp2(fminf(x - M[r], 100.f));
                        }
                    } else {
#pragma unroll 1
                        for (int c = 0; c < 32; ++c) {
                            int j = c*64 + lane;
                            float4 d = sjall[colOff + j];
                            float aw = fmaf(cohLoad(&pin[j]), INVK, d.w);
                            float x  = fmaf(qx[r], d.x, fmaf(qy[r], d.y, fmaf(qz[r], d.z, aw)));
                            s1 += fexp2(fminf(x - M[r], 100.f));
                        }
                    }
                    s4[r] = s1;
                }
            }
#pragma unroll
            for (int r = 0; r < RPW; ++r) {
                float sv = s4[r];
                for (int off = 1; off < 64; off <<= 1) sv += __shfl_xor(sv, off, 64);
                L[r] = M[r] + flog2(fmaxf(sv, 1e-37f));
            }
#pragma unroll
            for (int r = 0; r < RPW; ++r) {
                if (odd) LpG[r] = L[r]; else LpF[r] = L[r];
                if (lane == 0) cohStore(&pout[row0 + r], pc[r] - KS * L[r]);
            }
        } else {
            // ---- dense-type: stage sa, full sweep ----
            for (int t = threadIdx.x; t < NN; t += TPB)
                sa[t] = cohLoad(&pin[t]) * INVK;
            __syncthreads();

            if (pass < ONLINE_PASSES) {
                float m[RPW], s[RPW];
#pragma unroll
                for (int r = 0; r < RPW; ++r) { m[r] = -1e30f; s[r] = 0.f; }
#pragma unroll 2
                for (int c = 0; c < 32; ++c) {
                    float4 d = sjall[colOff + c*64 + lane];
                    float aw = d.w + sa[c*64 + lane];
#pragma unroll
                    for (int r = 0; r < RPW; ++r) {
                        float x  = fmaf(qx[r], d.x, fmaf(qy[r], d.y, fmaf(qz[r], d.z, aw)));
                        float mn = fmaxf(m[r], x);
                        s[r] = fmaf(s[r], fexp2(m[r]-mn), fexp2(x-mn));
                        m[r] = mn;
                    }
                }
#pragma unroll
                for (int r = 0; r < RPW; ++r) {
                    float mm = m[r], sv = s[r];
                    for (int off = 1; off < 64; off <<= 1) {
                        float mo = __shfl_xor(mm, off, 64);
                        float so = __shfl_xor(sv, off, 64);
                        float mn = fmaxf(mm, mo);
                        sv = fmaf(sv, fexp2(mm-mn), so * fexp2(mo-mn));
                        mm = mn;
                    }
                    float L = mm + flog2(fmaxf(sv, 1e-37f));
                    if (odd) LpG[r] = L; else LpF[r] = L;
                    if (lane == 0) cohStore(&pout[row0 + r], pc[r] - KS * L);
                }
            } else {
                float s[RPW]; int cn[RPW];
#pragma unroll
                for (int r = 0; r < RPW; ++r) { s[r] = 0.f; cn[r] = 0; }
#pragma unroll 1
                for (int c = 0; c < 32; ++c) {
                    int j = c*64 + lane;
                    float4 d = sjall[colOff + j];
                    float aw = d.w + sa[j];
#pragma unroll
                    for (int r = 0; r < RPW; ++r) {
                        float x = fmaf(qx[r], d.x, fmaf(qy[r], d.y, fmaf(qz[r], d.z, aw)));
                        s[r] += fexp2(fminf(x - M[r], 100.f));
                        bool pred = (x >= M[r] - MARGIN);
                        unsigned long long mask = __ballot((int)pred);
                        if (pred) {
                            int pos = cn[r] + __popcll(mask & ((1ull << lane) - 1ull));
                            if (pos < CAP) slist[odd][rowL0 + r][pos] = (unsigned short)j;
                        }
                        cn[r] += __popcll(mask);
                    }
                }
#pragma unroll
                for (int r = 0; r < RPW; ++r) {
                    float sv = s[r];
                    for (int off = 1; off < 64; off <<= 1) sv += __shfl_xor(sv, off, 64);
                    float L = M[r] + flog2(fmaxf(sv, 1e-37f));
                    if (odd) { LpG[r] = L; cnG[r] = cn[r]; }
                    else     { LpF[r] = L; cnF[r] = cn[r]; }
                    if (lane == 0) cohStore(&pout[row0 + r], pc[r] - KS * L);
                }
            }
        }
        barrier_sync(bar, rb, pass + 1);
    }

    // ---- dis: sum P*C over f-lists (side 0), direct pot loads ----
    {
        float acc[RPW];
#pragma unroll
        for (int r = 0; r < RPW; ++r) acc[r] = 0.f;
#pragma unroll
        for (int r = 0; r < RPW; ++r) {
            const int cnt = cnF[r];
            const unsigned short* lb = slist[0][rowL0 + r];
            const float bb2 = C1K - LpF[r];
            const float pn  = pcf[r] - C1V;
            float aa = 0.f;
            if (cnt <= CAP) {
#pragma unroll 1
                for (int k = lane; k < cnt; k += 64) {
                    int j = lb[k];
                    float4 d = sjall[j];
                    float aw = fmaf(cohLoad(&gb[j]), INVK, d.w);
                    float dot = fmaf(qxf[r], d.x, fmaf(qyf[r], d.y, qzf[r]*d.z));
                    float y   = dot + aw + bb2;
                    float e   = fexp2(fminf(y, 80.f));
                    aa = fmaf(e, fmaf(-KS, dot, pn - KS*d.w), aa);
                }
            } else {
#pragma unroll 1
                for (int c = 0; c < 32; ++c) {
                    int j = c*64 + lane;
                    float4 d = sjall[j];
                    float aw = fmaf(cohLoad(&gb[j]), INVK, d.w);
                    float dot = fmaf(qxf[r], d.x, fmaf(qyf[r], d.y, qzf[r]*d.z));
                    float y   = dot + aw + bb2;
                    float e   = fexp2(fminf(y, 80.f));
                    aa = fmaf(e, fmaf(-KS, dot, pn - KS*d.w), aa);
                }
            }
            acc[r] = aa;
        }
        float tot = acc[0] + acc[1] + acc[2] + acc[3];
        for (int off = 1; off < 64; off <<= 1) tot += __shfl_xor(tot, off, 64);
        if (lane == 0) wred[wave] = tot;
        __syncthreads();
        if (threadIdx.x == 0) {
            float v = 0.f;
            for (int w = 0; w < 16; ++w) v += wred[w];
            cohStore(&partials[blk], v);
        }
    }

    barrier_ctr(gctr, GRID_BLOCKS);

    if (blk == 0) {
        float v = (threadIdx.x < GRID_BLOCKS) ? cohLoad(&partials[threadIdx.x]) : 0.f;
        for (int off = 1; off < 64; off <<= 1) v += __shfl_xor(v, off, 64);
        if (lane == 0) wred[wave] = v;
        __syncthreads();
        if (threadIdx.x == 0) {
            float t2 = 0.f;
            for (int w = 0; w < 16; ++w) t2 += wred[w];
            out[0] = t2 * (1.0f / BB);
        }
    }
}

extern "C" void kernel_launch(void* const* d_in, const int* in_sizes, int n_in,
                              void* d_out, int out_size, void* d_ws, size_t ws_size,
                              hipStream_t stream) {
    const float* preds = (const float*)d_in[0];
    const float* gts   = (const float*)d_in[1];
    float* fp       = (float*)d_ws;
    float* gp       = fp + BB * NN;
    float* partials = gp + BB * NN;
    int*   barArr   = (int*)(partials + GRID_BLOCKS);  // 8 x 64 ints
    int*   gctr     = barArr + BB * 64;                // [32]
    float* out      = (float*)d_out;

    size_t zbytes = (size_t)(2 * BB * NN + GRID_BLOCKS) * sizeof(float)
                  + (size_t)(BB * 64 + 32) * sizeof(int);
    hipMemsetAsync(d_ws, 0, zbytes, stream);

    emd_persist<<<dim3(GRID_BLOCKS), dim3(TPB), 0, stream>>>(
        preds, gts, fp, gp, partials, barArr, gctr, out);
}